// Round 1
// baseline (1537.780 us; speedup 1.0000x reference)
//
#include <hip/hip_runtime.h>
#include <hip/hip_bf16.h>

typedef __attribute__((ext_vector_type(8))) short short8;
typedef __attribute__((ext_vector_type(4))) float float4v;

__device__ __forceinline__ unsigned short f2bf(float f) {
    union { float f; unsigned u; } v; v.f = f;
    unsigned r = v.u + 0x7fffu + ((v.u >> 16) & 1u);   // round-to-nearest-even
    return (unsigned short)(r >> 16);
}

// ---------------- K1: LayerNorm + ReLU, one wave per row ----------------
__global__ __launch_bounds__(256) void ln_relu_kernel(
    const float* __restrict__ x, const float* __restrict__ gamma,
    const float* __restrict__ beta, float* __restrict__ hbuf) {
    const int row  = blockIdx.x * 4 + (threadIdx.x >> 6);
    const int lane = threadIdx.x & 63;
    const size_t base = (size_t)row * 128 + lane * 2;
    float2 v = *(const float2*)&x[base];
    float s = v.x + v.y;
    #pragma unroll
    for (int o = 32; o; o >>= 1) s += __shfl_xor(s, o, 64);
    const float mu = s * 0.0078125f;                    // /128
    const float d0 = v.x - mu, d1 = v.y - mu;
    float ss = d0 * d0 + d1 * d1;
    #pragma unroll
    for (int o = 32; o; o >>= 1) ss += __shfl_xor(ss, o, 64);
    const float rs = rsqrtf(ss * 0.0078125f + 1e-5f);
    float2 g = *(const float2*)&gamma[lane * 2];
    float2 b = *(const float2*)&beta[lane * 2];
    float h0 = fmaxf(fmaf(d0 * rs, g.x, b.x), 0.f);
    float h1 = fmaxf(fmaf(d1 * rs, g.y, b.y), 0.f);
    *(float2*)&hbuf[base] = make_float2(h0, h1);
}

// ---------------- K2: pack W fragments (bf16, MFMA B-operand layout) ----
// Wc[n][k] = k<128 ? W_l[n][k] : W_r[n][k-128].  b_frag element j of lane l,
// col-tile t, k-chunk c:  Wc[t*16+(l&15)][c*32+(l>>4)*8+j].
__global__ __launch_bounds__(256) void wprep_kernel(
    const float* __restrict__ Wl, const float* __restrict__ Wr,
    unsigned short* __restrict__ wsb) {
    const int s = blockIdx.x * 256 + threadIdx.x;       // 0..4095
    const int t = s >> 9, c = (s >> 6) & 7, l = s & 63;
    const int n  = t * 16 + (l & 15);
    const int k0 = c * 32 + ((l >> 4) & 3) * 8;
    const float* w = (k0 < 128) ? (Wl + (size_t)n * 128 + k0)
                                : (Wr + (size_t)n * 128 + (k0 - 128));
    unsigned short tmp[8];
    #pragma unroll
    for (int j = 0; j < 8; j++) tmp[j] = f2bf(w[j]);
    *(short8*)&wsb[(size_t)s * 8] = *(short8*)tmp;
}

// ---------------- K3: edge scatter (mean numerator + degree) ------------
__global__ __launch_bounds__(256) void scatter_kernel(
    const int* __restrict__ idx, const float* __restrict__ hbuf,
    float* __restrict__ agg, float* __restrict__ cnt, int E) {
    const int e    = blockIdx.x * 4 + (threadIdx.x >> 6);
    const int lane = threadIdx.x & 63;
    const int src = idx[e];
    const int dst = idx[E + e];
    float2 v = *(const float2*)&hbuf[(size_t)src * 128 + lane * 2];
    float* base = &agg[(size_t)dst * 128 + lane * 2];
    if (v.x != 0.f) atomicAdd(base, v.x);       // ReLU zeros ~50% of entries
    if (v.y != 0.f) atomicAdd(base + 1, v.y);
    if (lane == 0) atomicAdd(&cnt[dst], 1.0f);
}

// ---------------- K4: fused mean + GEMM(bf16 MFMA) + bias + residual ----
// out[i][:] = (agg[i]/max(cnt,1) if cnt>0 else 0) @ W_l^T + b_l + h[i] @ W_r^T + x[i]
// agg aliases out (read fully before overwrite, block-local, after barrier).
__global__ __launch_bounds__(256) void fused_out_kernel(
    float* __restrict__ out /* == agg */, const float* __restrict__ cnt,
    const float* __restrict__ hbuf, const float* __restrict__ x,
    const unsigned short* __restrict__ wsb, const float* __restrict__ bl) {
    __shared__ unsigned short a_lds[8][64][8];          // [k-chunk][slot][j]
    const int t    = threadIdx.x;
    const int row0 = blockIdx.x * 16;

    // ---- stage z = [mean(128) || h(128)] for 16 rows, bf16, frag layout
    {
        const int r = t >> 4, seg = t & 15;             // 16 threads/row, 16 k each
        const int row = row0 + r;
        const int k0 = seg * 16;
        float z[16];
        if (seg < 8) {
            const float cv = cnt[row];
            const float inv = (cv > 0.f) ? (1.f / cv) : 0.f;
            const float4v* src = (const float4v*)&out[(size_t)row * 128 + k0];
            #pragma unroll
            for (int i = 0; i < 4; i++) {
                float4v v = src[i];
                z[i*4+0] = v.x*inv; z[i*4+1] = v.y*inv; z[i*4+2] = v.z*inv; z[i*4+3] = v.w*inv;
            }
        } else {
            const float4v* src = (const float4v*)&hbuf[(size_t)row * 128 + (k0 - 128)];
            #pragma unroll
            for (int i = 0; i < 4; i++) {
                float4v v = src[i];
                z[i*4+0] = v.x; z[i*4+1] = v.y; z[i*4+2] = v.z; z[i*4+3] = v.w;
            }
        }
        const int c = seg >> 1;
        #pragma unroll
        for (int half = 0; half < 2; half++) {
            const int q = ((seg & 1) << 1) + half;
            const int slot = q * 16 + r;
            unsigned short tmp[8];
            #pragma unroll
            for (int j = 0; j < 8; j++) tmp[j] = f2bf(z[half * 8 + j]);
            *(short8*)&a_lds[c][slot][0] = *(short8*)tmp;
        }
    }
    __syncthreads();

    // ---- MFMA: each wave computes 16 rows x 2 col-tiles (16 cols each)
    const int w = t >> 6, l = t & 63;
    short8 af[8];
    #pragma unroll
    for (int c = 0; c < 8; c++) af[c] = *(const short8*)&a_lds[c][l][0];

    float4v acc[2] = {{0.f,0.f,0.f,0.f},{0.f,0.f,0.f,0.f}};
    #pragma unroll
    for (int tt = 0; tt < 2; tt++) {
        const int tc = w * 2 + tt;
        const short8* bw = (const short8*)(wsb + (size_t)tc * 8 * 64 * 8);
        #pragma unroll
        for (int c = 0; c < 8; c++) {
            short8 bf = bw[c * 64 + l];
            acc[tt] = __builtin_amdgcn_mfma_f32_16x16x32_bf16(af[c], bf, acc[tt], 0, 0, 0);
        }
    }

    // ---- epilogue: + b_l + x, write out (C/D: col=lane&15, row=quad*4+reg)
    #pragma unroll
    for (int tt = 0; tt < 2; tt++) {
        const int col = (w * 2 + tt) * 16 + (l & 15);
        const float blv = bl[col];
        #pragma unroll
        for (int rr = 0; rr < 4; rr++) {
            const int row = row0 + (l >> 4) * 4 + rr;
            out[(size_t)row * 128 + col] = acc[tt][rr] + blv + x[(size_t)row * 128 + col];
        }
    }
}

extern "C" void kernel_launch(void* const* d_in, const int* in_sizes, int n_in,
                              void* d_out, int out_size, void* d_ws, size_t ws_size,
                              hipStream_t stream) {
    const float* x     = (const float*)d_in[0];
    const int*   ei    = (const int*)d_in[1];
    const float* gamma = (const float*)d_in[2];
    const float* beta  = (const float*)d_in[3];
    const float* Wl    = (const float*)d_in[4];
    const float* bl    = (const float*)d_in[5];
    const float* Wr    = (const float*)d_in[6];
    float* out = (float*)d_out;

    const int C = 128;
    const int N = in_sizes[0] / C;          // 100000
    const int E = in_sizes[1] / 2;          // 1600000

    char* ws = (char*)d_ws;
    float* hbuf = (float*)ws;                                   // N*C fp32
    float* cnt  = (float*)(ws + (size_t)N * C * 4);             // N fp32
    unsigned short* wsb = (unsigned short*)(ws + (size_t)N * C * 4 + (size_t)N * 4); // 64 KiB

    hipMemsetAsync(out, 0, (size_t)N * C * 4, stream);  // agg accumulates in d_out
    hipMemsetAsync(cnt, 0, (size_t)N * 4, stream);

    ln_relu_kernel<<<N / 4, 256, 0, stream>>>(x, gamma, beta, hbuf);
    wprep_kernel<<<16, 256, 0, stream>>>(Wl, Wr, wsb);
    scatter_kernel<<<E / 4, 256, 0, stream>>>(ei, hbuf, out, cnt, E);
    fused_out_kernel<<<N / 16, 256, 0, stream>>>(out, cnt, hbuf, x, wsb, bl);
}

// Round 2
// 368.677 us; speedup vs baseline: 4.1711x; 4.1711x over previous
//
#include <hip/hip_runtime.h>
#include <hip/hip_bf16.h>

typedef __attribute__((ext_vector_type(8))) short short8;
typedef __attribute__((ext_vector_type(4))) float float4v;

#define CAP 48   // per-node edge slots; deg ~ Poisson(16), P(>48) ~ 1e-11; fallback below keeps correctness

__device__ __forceinline__ unsigned short f2bf(float f) {
    union { float f; unsigned u; } v; v.f = f;
    unsigned r = v.u + 0x7fffu + ((v.u >> 16) & 1u);   // round-to-nearest-even
    return (unsigned short)(r >> 16);
}
__device__ __forceinline__ float bf2f(unsigned short u) {
    union { unsigned u; float f; } v; v.u = ((unsigned)u) << 16; return v.f;
}

// ---------------- K1: LayerNorm + ReLU -> packed bf16 h ----------------
__global__ __launch_bounds__(256) void ln_relu_kernel(
    const float* __restrict__ x, const float* __restrict__ gamma,
    const float* __restrict__ beta, unsigned* __restrict__ hbuf, int N) {
    const int row  = blockIdx.x * 4 + (threadIdx.x >> 6);
    if (row >= N) return;
    const int lane = threadIdx.x & 63;
    const size_t base = (size_t)row * 128 + lane * 2;
    float2 v = *(const float2*)&x[base];
    float s = v.x + v.y;
    #pragma unroll
    for (int o = 32; o; o >>= 1) s += __shfl_xor(s, o, 64);
    const float mu = s * 0.0078125f;
    const float d0 = v.x - mu, d1 = v.y - mu;
    float ss = d0 * d0 + d1 * d1;
    #pragma unroll
    for (int o = 32; o; o >>= 1) ss += __shfl_xor(ss, o, 64);
    const float rs = rsqrtf(ss * 0.0078125f + 1e-5f);
    float2 g = *(const float2*)&gamma[lane * 2];
    float2 b = *(const float2*)&beta[lane * 2];
    float h0 = fmaxf(fmaf(d0 * rs, g.x, b.x), 0.f);
    float h1 = fmaxf(fmaf(d1 * rs, g.y, b.y), 0.f);
    hbuf[(size_t)row * 64 + lane] =
        (unsigned)f2bf(h0) | ((unsigned)f2bf(h1) << 16);
}

// ---------------- K2: pack W fragments (bf16, MFMA B-operand layout) ----
// Wc[n][k] = k<128 ? W_l[n][k] : W_r[n][k-128].
__global__ __launch_bounds__(256) void wprep_kernel(
    const float* __restrict__ Wl, const float* __restrict__ Wr,
    unsigned short* __restrict__ wsb) {
    const int s = blockIdx.x * 256 + threadIdx.x;       // 0..4095
    const int t = s >> 9, c = (s >> 6) & 7, l = s & 63;
    const int n  = t * 16 + (l & 15);
    const int k0 = c * 32 + ((l >> 4) & 3) * 8;
    const float* w = (k0 < 128) ? (Wl + (size_t)n * 128 + k0)
                                : (Wr + (size_t)n * 128 + (k0 - 128));
    unsigned short tmp[8];
    #pragma unroll
    for (int j = 0; j < 8; j++) tmp[j] = f2bf(w[j]);
    *(short8*)&wsb[(size_t)s * 8] = *(short8*)tmp;
}

// ---------------- K3: build per-dst adjacency (int atomics only) --------
__global__ __launch_bounds__(256) void build_edges_kernel(
    const int* __restrict__ idx, const unsigned* __restrict__ hbuf,
    float* __restrict__ out, int* __restrict__ deg, int* __restrict__ elist,
    int E) {
    const int e = blockIdx.x * 256 + threadIdx.x;
    if (e >= E) return;
    const int src = idx[e];
    const int dst = idx[E + e];
    const int pos = atomicAdd(&deg[dst], 1);
    if (pos < CAP) {
        elist[(size_t)dst * CAP + pos] = src;
    } else {
        // near-impossible overflow: fall back to fp atomics into out (pre-zeroed)
        const unsigned* hp = hbuf + (size_t)src * 64;
        float* op = out + (size_t)dst * 128;
        for (int c = 0; c < 64; c++) {
            unsigned p = hp[c];
            float v0 = bf2f((unsigned short)(p & 0xffffu));
            float v1 = bf2f((unsigned short)(p >> 16));
            if (v0 != 0.f) atomicAdd(op + 2 * c, v0);
            if (v1 != 0.f) atomicAdd(op + 2 * c + 1, v1);
        }
    }
}

// ---------------- K4: gather-reduce + mean + MFMA GEMM + bias + residual
// out[i][:] = mean_j h[j] @ W_l^T + b_l + h[i] @ W_r^T + x[i]
// Requires N % 16 == 0 (true: N=100000).
__global__ __launch_bounds__(256) void fused_out_kernel(
    float* __restrict__ out, const int* __restrict__ deg,
    const unsigned* __restrict__ hbuf, const float* __restrict__ x,
    const unsigned short* __restrict__ wsb, const float* __restrict__ bl,
    const int* __restrict__ elist) {
    __shared__ float smem_agg[16][128];                 // 8 KB
    __shared__ unsigned short a_lds[8][64][8];          // 8 KB
    const int t = threadIdx.x, w = t >> 6, l = t & 63;
    const int row0 = blockIdx.x * 16;

    // ---- Phase 1: wave w gathers+reduces rows w*4 .. w*4+3
    #pragma unroll
    for (int i = 0; i < 4; i++) {
        const int lr = w * 4 + i;
        const int row = row0 + lr;
        const int dv = deg[row];
        const int dcl = dv < CAP ? dv : CAP;
        const int* ep = elist + (size_t)row * CAP;
        float a0 = 0.f, a1 = 0.f;
        int j = 0;
        for (; j + 4 <= dcl; j += 4) {
            int4 s4 = *(const int4*)(ep + j);
            unsigned p0 = hbuf[(size_t)s4.x * 64 + l];
            unsigned p1 = hbuf[(size_t)s4.y * 64 + l];
            unsigned p2 = hbuf[(size_t)s4.z * 64 + l];
            unsigned p3 = hbuf[(size_t)s4.w * 64 + l];
            a0 += bf2f((unsigned short)(p0 & 0xffffu)) + bf2f((unsigned short)(p1 & 0xffffu))
                + bf2f((unsigned short)(p2 & 0xffffu)) + bf2f((unsigned short)(p3 & 0xffffu));
            a1 += bf2f((unsigned short)(p0 >> 16)) + bf2f((unsigned short)(p1 >> 16))
                + bf2f((unsigned short)(p2 >> 16)) + bf2f((unsigned short)(p3 >> 16));
        }
        for (; j < dcl; j++) {
            unsigned p = hbuf[(size_t)ep[j] * 64 + l];
            a0 += bf2f((unsigned short)(p & 0xffffu));
            a1 += bf2f((unsigned short)(p >> 16));
        }
        if (dv > CAP) {                                  // overflow rows: add atomic-accumulated part
            float2 pv = *(const float2*)&out[(size_t)row * 128 + 2 * l];
            a0 += pv.x; a1 += pv.y;
        }
        smem_agg[lr][2 * l]     = a0;
        smem_agg[lr][2 * l + 1] = a1;
    }
    __syncthreads();

    // ---- Phase 2: stage z = [mean(128) || h(128)] into MFMA A-frag layout
    {
        const int r = t >> 4, seg = t & 15;
        const int row = row0 + r;
        const int c = seg >> 1;
        unsigned short tmp[16];
        if (seg < 8) {
            const int dv = deg[row];
            const float inv = (dv > 0) ? (1.f / (float)dv) : 0.f;
            const int k0 = seg * 16;
            #pragma unroll
            for (int i2 = 0; i2 < 16; i2++)
                tmp[i2] = f2bf(smem_agg[r][k0 + i2] * inv);
        } else {
            const unsigned short* hp =
                (const unsigned short*)hbuf + (size_t)row * 128 + (seg - 8) * 16;
            #pragma unroll
            for (int i2 = 0; i2 < 16; i2++) tmp[i2] = hp[i2];
        }
        #pragma unroll
        for (int half = 0; half < 2; half++) {
            const int q = ((seg & 1) << 1) + half;
            *(short8*)&a_lds[c][q * 16 + r][0] = *(short8*)&tmp[half * 8];
        }
    }
    __syncthreads();

    // ---- Phase 3: MFMA — wave computes 16 rows x 2 col-tiles
    short8 af[8];
    #pragma unroll
    for (int c = 0; c < 8; c++) af[c] = *(const short8*)&a_lds[c][l][0];

    float4v acc[2] = {{0.f,0.f,0.f,0.f},{0.f,0.f,0.f,0.f}};
    #pragma unroll
    for (int tt = 0; tt < 2; tt++) {
        const int tc = w * 2 + tt;
        const short8* bw = (const short8*)(wsb + (size_t)tc * 8 * 64 * 8);
        #pragma unroll
        for (int c = 0; c < 8; c++) {
            short8 bf = bw[c * 64 + l];
            acc[tt] = __builtin_amdgcn_mfma_f32_16x16x32_bf16(af[c], bf, acc[tt], 0, 0, 0);
        }
    }

    // ---- Phase 4: epilogue (+b_l +x), C/D layout: col=lane&15, row=quad*4+reg
    #pragma unroll
    for (int tt = 0; tt < 2; tt++) {
        const int col = (w * 2 + tt) * 16 + (l & 15);
        const float blv = bl[col];
        #pragma unroll
        for (int rr = 0; rr < 4; rr++) {
            const int row = row0 + (l >> 4) * 4 + rr;
            out[(size_t)row * 128 + col] = acc[tt][rr] + blv + x[(size_t)row * 128 + col];
        }
    }
}

extern "C" void kernel_launch(void* const* d_in, const int* in_sizes, int n_in,
                              void* d_out, int out_size, void* d_ws, size_t ws_size,
                              hipStream_t stream) {
    const float* x     = (const float*)d_in[0];
    const int*   ei    = (const int*)d_in[1];
    const float* gamma = (const float*)d_in[2];
    const float* beta  = (const float*)d_in[3];
    const float* Wl    = (const float*)d_in[4];
    const float* bl    = (const float*)d_in[5];
    const float* Wr    = (const float*)d_in[6];
    float* out = (float*)d_out;

    const int C = 128;
    const int N = in_sizes[0] / C;          // 100000
    const int E = in_sizes[1] / 2;          // 1600000

    char* ws = (char*)d_ws;
    unsigned* hbuf = (unsigned*)ws;                                  // N*64 u32 (packed bf16) = 25.6 MB
    int* deg   = (int*)(ws + (size_t)N * 256);                       // N i32
    int* elist = (int*)(ws + (size_t)N * 256 + (size_t)N * 4);       // N*CAP i32 = 19.2 MB
    unsigned short* wsb =
        (unsigned short*)(ws + (size_t)N * 256 + (size_t)N * 4 + (size_t)N * CAP * 4); // 64 KiB

    hipMemsetAsync(out, 0, (size_t)N * C * 4, stream);   // only needed for overflow fallback
    hipMemsetAsync(deg, 0, (size_t)N * 4, stream);

    ln_relu_kernel<<<(N + 3) / 4, 256, 0, stream>>>(x, gamma, beta, hbuf, N);
    wprep_kernel<<<16, 256, 0, stream>>>(Wl, Wr, wsb);
    build_edges_kernel<<<(E + 255) / 256, 256, 0, stream>>>(ei, hbuf, out, deg, elist, E);
    fused_out_kernel<<<N / 16, 256, 0, stream>>>(out, deg, hbuf, x, wsb, bl, elist);
}